// Round 14
// baseline (178.557 us; speedup 1.0000x reference)
//
#include <hip/hip_runtime.h>
#include <hip/hip_bf16.h>
#include <math.h>

#define CIN 256
#define COUT 512

typedef __attribute__((ext_vector_type(8))) short bf16x8;
typedef __attribute__((ext_vector_type(4))) float f32x4;
typedef __attribute__((ext_vector_type(4))) float f32x4v;

__device__ __forceinline__ ushort f2bf(float f) {
    union { float f; unsigned u; } x; x.f = f;
    unsigned r = x.u + 0x7FFFu + ((x.u >> 16) & 1u);   // RNE
    return (ushort)(r >> 16);
}

__device__ __forceinline__ int lbound(const int* __restrict__ a, int n, int key) {
    int lo = 0, hi = n;
    while (lo < hi) {
        int m = (lo + hi) >> 1;
        if (a[m] < key) lo = m + 1; else hi = m;
    }
    return lo;
}

// ---------------------------------------------------------------------------
// Kernel A: prep blocks first, then pool (R10-exact pool inner loop).
// Single addition vs R13: block 0 resets the gate counter (graph-replay safe:
// A always precedes B on the stream).
// ---------------------------------------------------------------------------
__global__ __launch_bounds__(256) void pool_prep_kernel(const float* __restrict__ data,
                                                        const int* __restrict__ idx5, int n_i5,
                                                        const int* __restrict__ idx4, int n_i4,
                                                        const float* __restrict__ W,
                                                        ushort* __restrict__ Wb,
                                                        ushort* __restrict__ P, int G2,
                                                        int* __restrict__ inv4, int n4,
                                                        unsigned* __restrict__ gate) {
    const int b = blockIdx.x;
    const int t = threadIdx.x;

    if (b < 32) {                            // W conversion: 32 blocks
        if (b == 0 && t == 0) *gate = 0;     // reset B's arrival counter
        int q0 = b * 1024 + t;
        #pragma unroll
        for (int j = 0; j < 4; ++j) {
            int i = (q0 + j * 256) * 4;
            float4 v = *reinterpret_cast<const float4*>(W + i);
            ushort4 o;
            o.x = f2bf(v.x); o.y = f2bf(v.y); o.z = f2bf(v.z); o.w = f2bf(v.w);
            *reinterpret_cast<ushort4*>(&Wb[i]) = o;
        }
        return;
    }
    if (b < 96) {                            // inv4 build: 64 blocks
        int i = (b - 32) * 256 + t;
        if (i < n_i4) {
            int s = idx4[i];
            inv4[s] = i;
            int e = (i + 1 < n_i4) ? idx4[i + 1] : n4;
            for (int k = s + 1; k < e; ++k) inv4[k] = -1;
            if (i == 0) for (int k = 0; k < s; ++k) inv4[k] = -1;
        }
        return;
    }

    const int pb = b - 96;                   // pool block: rows pb*4..+3
    __shared__ int lb[5];
    if (t < 5) lb[t] = lbound(idx5, n_i5, pb * 32 + t * 8);
    __syncthreads();

    const int w = t >> 6, lane = t & 63;
    int lo  = __builtin_amdgcn_readfirstlane(lb[w]);
    int cnt = __builtin_amdgcn_readfirstlane(lb[w + 1]) - lo;   // 0..8 occupied

    float4 acc = make_float4(-INFINITY, -INFINITY, -INFINITY, -INFINITY);
    const float* base = data + (size_t)lo * (8 * CIN) + lane * 4;
    #pragma unroll
    for (int j = 0; j < 8; ++j) {
        if (j < cnt) {                       // wave-uniform predicate, unrolled
            #pragma unroll
            for (int r = 0; r < 8; ++r) {
                f32x4v v = __builtin_nontemporal_load(
                    reinterpret_cast<const f32x4v*>(base + ((size_t)j * 8 + r) * CIN));
                acc.x = fmaxf(acc.x, v.x);
                acc.y = fmaxf(acc.y, v.y);
                acc.z = fmaxf(acc.z, v.z);
                acc.w = fmaxf(acc.w, v.w);
            }
        }
    }
    if (cnt < 8) {                           // empty slots contribute 0 (also cnt==0)
        acc.x = fmaxf(acc.x, 0.f);
        acc.y = fmaxf(acc.y, 0.f);
        acc.z = fmaxf(acc.z, 0.f);
        acc.w = fmaxf(acc.w, 0.f);
    }
    ushort4 o;
    o.x = f2bf(acc.x); o.y = f2bf(acc.y); o.z = f2bf(acc.z); o.w = f2bf(acc.w);
    *reinterpret_cast<ushort4*>(&P[(size_t)(pb * 4 + w) * CIN + lane * 4]) = o;
}

// ---------------------------------------------------------------------------
// Kernel B'': champion GEMM+stats, then device-scope atomic gate (all 512
// blocks co-resident at 2 blocks/CU), then per-block BN finalize of its own
// 128 cols, apply BN+ReLU to LIVE fp32 accumulators, LDS-transpose scatter,
// and empty-row fill. H never touches HBM; kernels C and D are gone.
// ---------------------------------------------------------------------------
__global__ __launch_bounds__(256, 2) void gemm_fused_kernel(
    const ushort* __restrict__ A,
    const ushort* __restrict__ B,
    const float* __restrict__ gamma,
    const float* __restrict__ beta,
    const int* __restrict__ idx4,
    const int* __restrict__ inv4,
    float* __restrict__ partial,
    unsigned* __restrict__ gate,
    float* __restrict__ out,
    float invN, int nblocks)
{
    __shared__ __align__(16) ushort Asm[128 * 64];   // 16 KiB (4096 floats)
    __shared__ __align__(16) ushort Bsm[128 * 64];   // 16 KiB (outb reuse)

    int t = threadIdx.x;
    int lane = t & 63;
    int wid = t >> 6;
    int wm = wid >> 1, wn = wid & 1;
    int bm = blockIdx.x, bn = blockIdx.y;
    int m0 = bm * 128, n0 = bn * 128;

    f32x4 acc[4][4] = {};

    // ---- phase 1: GEMM (champion, byte-identical) ----
    for (int k0 = 0; k0 < CIN; k0 += 64) {
        #pragma unroll
        for (int i = 0; i < 4; ++i) {
            int idx = i * 256 + t;          // 0..1023
            int row = idx >> 3;
            int sl  = idx & 7;
            bf16x8 av = *reinterpret_cast<const bf16x8*>(A + (size_t)(m0 + row) * CIN + k0 + sl * 8);
            bf16x8 bv = *reinterpret_cast<const bf16x8*>(B + (size_t)(n0 + row) * CIN + k0 + sl * 8);
            int ws = (sl ^ (row & 7)) * 8;
            *reinterpret_cast<bf16x8*>(&Asm[row * 64 + ws]) = av;
            *reinterpret_cast<bf16x8*>(&Bsm[row * 64 + ws]) = bv;
        }
        __syncthreads();

        #pragma unroll
        for (int ks = 0; ks < 2; ++ks) {
            bf16x8 af[4], bfr[4];
            int slog = ks * 4 + (lane >> 4);
            #pragma unroll
            for (int mi = 0; mi < 4; ++mi) {
                int row = wm * 64 + mi * 16 + (lane & 15);
                af[mi] = *reinterpret_cast<const bf16x8*>(&Asm[row * 64 + (slog ^ (row & 7)) * 8]);
            }
            #pragma unroll
            for (int ni = 0; ni < 4; ++ni) {
                int col = wn * 64 + ni * 16 + (lane & 15);
                bfr[ni] = *reinterpret_cast<const bf16x8*>(&Bsm[col * 64 + (slog ^ (col & 7)) * 8]);
            }
            #pragma unroll
            for (int mi = 0; mi < 4; ++mi)
                #pragma unroll
                for (int ni = 0; ni < 4; ++ni)
                    acc[mi][ni] = __builtin_amdgcn_mfma_f32_16x16x32_bf16(af[mi], bfr[ni], acc[mi][ni], 0, 0, 0);
        }
        __syncthreads();
    }

    // ---- phase 2: block stats -> partial (champion) ----
    float s[4], q[4];
    #pragma unroll
    for (int ni = 0; ni < 4; ++ni) {
        s[ni] = 0.f; q[ni] = 0.f;
        #pragma unroll
        for (int mi = 0; mi < 4; ++mi)
            #pragma unroll
            for (int r = 0; r < 4; ++r) {
                float v = acc[mi][ni][r];
                s[ni] += v;
                q[ni] = fmaf(v, v, q[ni]);
            }
        s[ni] += __shfl_xor(s[ni], 16); s[ni] += __shfl_xor(s[ni], 32);
        q[ni] += __shfl_xor(q[ni], 16); q[ni] += __shfl_xor(q[ni], 32);
    }
    float* redS = (float*)Asm;             // LDS floats [0,256)
    float* redQ = redS + 256;              // [256,512)
    if (lane < 16) {
        #pragma unroll
        for (int ni = 0; ni < 4; ++ni) {
            int c = wn * 64 + ni * 16 + lane;
            redS[wm * 128 + c] = s[ni];
            redQ[wm * 128 + c] = q[ni];
        }
    }
    __syncthreads();
    if (t < 128) {
        float S = redS[t] + redS[128 + t];
        float Q = redQ[t] + redQ[128 + t];
        partial[(size_t)bm * 1024 + bn * 128 + t]       = S;
        partial[(size_t)bm * 1024 + 512 + bn * 128 + t] = Q;
    }

    // ---- phase 3: device-scope gate (all blocks co-resident by design) ----
    __threadfence();
    __syncthreads();
    if (t == 0) {
        __hip_atomic_fetch_add(gate, 1u, __ATOMIC_ACQ_REL, __HIP_MEMORY_SCOPE_AGENT);
        int spins = 0;
        while (__hip_atomic_load(gate, __ATOMIC_ACQUIRE, __HIP_MEMORY_SCOPE_AGENT) < (unsigned)nblocks
               && ++spins < 2000000) {
            __builtin_amdgcn_s_sleep(4);
        }
    }
    __syncthreads();

    // ---- phase 4: finalize this block's 128 cols (redundant across bm) ----
    {
        int half = t >> 7;                 // 0..1
        int c    = n0 + (t & 127);
        float S = 0.f, Q = 0.f;
        for (int p = half * 64; p < half * 64 + 64; ++p) {
            S += partial[(size_t)p * 1024 + c];
            Q += partial[(size_t)p * 1024 + 512 + c];
        }
        redS[t] = S;                       // reuse LDS scratch
        redQ[t] = Q;
    }
    __syncthreads();
    float* scl = redQ + 256;               // LDS floats [512,640)
    float* sht = scl + 128;                // [640,768)
    float* rsh = sht + 128;                // [768,896)
    if (t < 128) {
        float Sf = redS[t] + redS[t + 128];
        float Qf = redQ[t] + redQ[t + 128];
        float mean = Sf * invN;
        float var  = fmaf(Qf, invN, -mean * mean);
        float inv  = rsqrtf(var + 1e-5f);
        float sc   = gamma[n0 + t] * inv;
        float sh   = fmaf(-mean, sc, beta[n0 + t]);
        scl[t] = sc;
        sht[t] = sh;
        rsh[t] = fmaxf(sh, 0.f);
    }
    __syncthreads();

    // ---- phase 5: apply BN+ReLU from live acc, LDS transpose, scatter ----
    float* outb = (float*)Bsm;             // [32][128] floats = 16 KiB exactly
    #pragma unroll
    for (int mi = 0; mi < 4; ++mi) {
        __syncthreads();
        #pragma unroll
        for (int ni = 0; ni < 4; ++ni) {
            int lc = wn * 64 + ni * 16 + (lane & 15);
            float sc_ = scl[lc], sh_ = sht[lc];
            int r0 = (lane >> 4) * 4;
            #pragma unroll
            for (int r = 0; r < 4; ++r)
                outb[(wm * 16 + r0 + r) * 128 + lc] =
                    fmaxf(fmaf(acc[mi][ni][r], sc_, sh_), 0.f);
        }
        __syncthreads();
        #pragma unroll
        for (int it = 0; it < 2; ++it) {
            int rr   = it * 16 + (t >> 4);                    // 0..31 staged row
            int lrow = (rr < 16) ? (mi * 16 + rr) : (64 + mi * 16 + (rr - 16));
            int grow = idx4[m0 + lrow];
            float* dst = out + (size_t)grow * COUT + n0 + (t & 15) * 8;
            float4 v0 = *reinterpret_cast<float4*>(&outb[rr * 128 + (t & 15) * 8]);
            float4 v1 = *reinterpret_cast<float4*>(&outb[rr * 128 + (t & 15) * 8 + 4]);
            *reinterpret_cast<float4*>(dst)     = v0;
            *reinterpret_cast<float4*>(dst + 4) = v1;
        }
    }

    // ---- phase 6: empty-row fill, rows [bm*256,+256) x cols [n0,+128) ----
    __syncthreads();
    {
        int base = bm * 256 + wid * 64;    // each wave: 64 rows
        int e = inv4[base + lane];
        float2 f0 = *reinterpret_cast<float2*>(&rsh[lane * 2]);
        for (int r = 0; r < 64; ++r) {
            if (__shfl(e, r) < 0) {        // wave-uniform
                float* dst = out + (size_t)(base + r) * COUT + n0 + lane * 2;
                *reinterpret_cast<float2*>(dst) = f0;
            }
        }
    }
}

// ---------------------------------------------------------------------------
extern "C" void kernel_launch(void* const* d_in, const int* in_sizes, int n_in,
                              void* d_out, int out_size, void* d_ws, size_t ws_size,
                              hipStream_t stream) {
    const float* data   = (const float*)d_in[0];
    const float* weight = (const float*)d_in[1];
    const float* gamma  = (const float*)d_in[2];
    const float* beta   = (const float*)d_in[3];
    const int*   idx5   = (const int*)d_in[4];
    const int*   idx4   = (const int*)d_in[5];

    const int n_i5 = in_sizes[4];        // 65536
    const int n_i4 = in_sizes[5];        // 16384
    const int G2   = n_i4;
    const int rows = out_size / COUT;    // 32768
    const int M    = G2;                 // 16384
    const int MB   = M / 128;            // 128 m-tiles
    const int NB   = MB * 4;             // 512 fused blocks

    // workspace layout
    char* w = (char*)d_ws;
    ushort*   P       = (ushort*)w;                     w += (size_t)G2 * CIN * sizeof(ushort);   // 8 MiB
    ushort*   Wb      = (ushort*)w;                     w += (size_t)COUT * CIN * sizeof(ushort); // 0.25 MiB
    float*    partial = (float*)w;                      w += (size_t)MB * 1024 * sizeof(float);   // 512 KiB
    int*      inv4    = (int*)w;                        w += (size_t)rows * sizeof(int);          // 128 KiB
    unsigned* gate    = (unsigned*)w;                   w += 256;                                  // counter

    // A: prep (96 blocks first, incl. gate reset) + pool (G2/4 blocks)
    pool_prep_kernel<<<96 + G2 / 4, 256, 0, stream>>>(
        data, idx5, n_i5, idx4, n_i4, weight, Wb, P, G2, inv4, rows, gate);

    // B'': GEMM + stats + gate + BN finalize + apply + scatter + empty fill
    {
        dim3 grid(MB, 4);
        gemm_fused_kernel<<<grid, 256, 0, stream>>>(
            P, Wb, gamma, beta, idx4, inv4, partial, gate,
            (float*)d_out, 1.0f / (float)rows, NB);
    }
}

// Round 15
// 130.250 us; speedup vs baseline: 1.3709x; 1.3709x over previous
//
#include <hip/hip_runtime.h>
#include <hip/hip_bf16.h>
#include <math.h>

#define CIN 256
#define COUT 512

typedef __attribute__((ext_vector_type(8))) short bf16x8;
typedef __attribute__((ext_vector_type(4))) float f32x4;
typedef __attribute__((ext_vector_type(4))) float f32x4v;

__device__ __forceinline__ ushort f2bf(float f) {
    union { float f; unsigned u; } x; x.f = f;
    unsigned r = x.u + 0x7FFFu + ((x.u >> 16) & 1u);   // RNE
    return (ushort)(r >> 16);
}
__device__ __forceinline__ float bf2f(ushort u) {
    union { unsigned u; float f; } x; x.u = (unsigned)u << 16; return x.f;
}

__device__ __forceinline__ int lbound(const int* __restrict__ a, int n, int key) {
    int lo = 0, hi = n;
    while (lo < hi) {
        int m = (lo + hi) >> 1;
        if (a[m] < key) lo = m + 1; else hi = m;
    }
    return lo;
}

// ---------------------------------------------------------------------------
// Kernel A: prep blocks first, then pool.
// R15 pool change (single variable vs R13 champion): TWO pooled rows per
// wave (block owns 8 groups) -> two independent NT load streams + fmax
// chains per wave, doubling in-flight bytes. NT + predicated unroll kept.
// ---------------------------------------------------------------------------
__global__ __launch_bounds__(256) void pool_prep_kernel(const float* __restrict__ data,
                                                        const int* __restrict__ idx5, int n_i5,
                                                        const int* __restrict__ idx4, int n_i4,
                                                        const float* __restrict__ W,
                                                        ushort* __restrict__ Wb,
                                                        ushort* __restrict__ P, int G2,
                                                        int* __restrict__ inv4, int n4) {
    const int b = blockIdx.x;
    const int t = threadIdx.x;

    if (b < 32) {                            // W conversion: 32 blocks
        int q0 = b * 1024 + t;
        #pragma unroll
        for (int j = 0; j < 4; ++j) {
            int i = (q0 + j * 256) * 4;
            float4 v = *reinterpret_cast<const float4*>(W + i);
            ushort4 o;
            o.x = f2bf(v.x); o.y = f2bf(v.y); o.z = f2bf(v.z); o.w = f2bf(v.w);
            *reinterpret_cast<ushort4*>(&Wb[i]) = o;
        }
        return;
    }
    if (b < 96) {                            // inv4 build: 64 blocks
        int i = (b - 32) * 256 + t;
        if (i < n_i4) {
            int s = idx4[i];
            inv4[s] = i;
            int e = (i + 1 < n_i4) ? idx4[i + 1] : n4;
            for (int k = s + 1; k < e; ++k) inv4[k] = -1;
            if (i == 0) for (int k = 0; k < s; ++k) inv4[k] = -1;
        }
        return;
    }

    const int pb = b - 96;                   // pool block: groups [8pb, 8pb+8)
    __shared__ int lb[9];
    if (t < 9) lb[t] = lbound(idx5, n_i5, pb * 64 + t * 8);
    __syncthreads();

    const int w = t >> 6, lane = t & 63;
    int lo0 = __builtin_amdgcn_readfirstlane(lb[2 * w]);
    int mid = __builtin_amdgcn_readfirstlane(lb[2 * w + 1]);
    int hi  = __builtin_amdgcn_readfirstlane(lb[2 * w + 2]);
    int cnt0 = mid - lo0;                    // occupied slots of group 2w   (0..8)
    int cnt1 = hi - mid;                     // occupied slots of group 2w+1 (0..8)

    float4 a0 = make_float4(-INFINITY, -INFINITY, -INFINITY, -INFINITY);
    float4 a1 = a0;
    const float* base0 = data + (size_t)lo0 * (8 * CIN) + lane * 4;
    const float* base1 = data + (size_t)mid * (8 * CIN) + lane * 4;
    #pragma unroll
    for (int j = 0; j < 8; ++j) {
        if (j < cnt0) {                      // stream 0 (wave-uniform predicate)
            #pragma unroll
            for (int r = 0; r < 8; ++r) {
                f32x4v v = __builtin_nontemporal_load(
                    reinterpret_cast<const f32x4v*>(base0 + ((size_t)j * 8 + r) * CIN));
                a0.x = fmaxf(a0.x, v.x);
                a0.y = fmaxf(a0.y, v.y);
                a0.z = fmaxf(a0.z, v.z);
                a0.w = fmaxf(a0.w, v.w);
            }
        }
        if (j < cnt1) {                      // stream 1 (independent chain)
            #pragma unroll
            for (int r = 0; r < 8; ++r) {
                f32x4v v = __builtin_nontemporal_load(
                    reinterpret_cast<const f32x4v*>(base1 + ((size_t)j * 8 + r) * CIN));
                a1.x = fmaxf(a1.x, v.x);
                a1.y = fmaxf(a1.y, v.y);
                a1.z = fmaxf(a1.z, v.z);
                a1.w = fmaxf(a1.w, v.w);
            }
        }
    }
    if (cnt0 < 8) {                          // empty slots contribute 0 (also cnt==0)
        a0.x = fmaxf(a0.x, 0.f);
        a0.y = fmaxf(a0.y, 0.f);
        a0.z = fmaxf(a0.z, 0.f);
        a0.w = fmaxf(a0.w, 0.f);
    }
    if (cnt1 < 8) {
        a1.x = fmaxf(a1.x, 0.f);
        a1.y = fmaxf(a1.y, 0.f);
        a1.z = fmaxf(a1.z, 0.f);
        a1.w = fmaxf(a1.w, 0.f);
    }
    ushort4 o0, o1;
    o0.x = f2bf(a0.x); o0.y = f2bf(a0.y); o0.z = f2bf(a0.z); o0.w = f2bf(a0.w);
    o1.x = f2bf(a1.x); o1.y = f2bf(a1.y); o1.z = f2bf(a1.z); o1.w = f2bf(a1.w);
    *reinterpret_cast<ushort4*>(&P[(size_t)(pb * 8 + 2 * w) * CIN + lane * 4])     = o0;
    *reinterpret_cast<ushort4*>(&P[(size_t)(pb * 8 + 2 * w + 1) * CIN + lane * 4]) = o1;
}

// ---------------------------------------------------------------------------
// Kernel B: bf16 MFMA GEMM + fused column stats (champion, byte-frozen).
// ---------------------------------------------------------------------------
__global__ __launch_bounds__(256) void mfma_gemm_kernel(const ushort* __restrict__ A,
                                                        const ushort* __restrict__ B,
                                                        ushort* __restrict__ H,
                                                        float* __restrict__ partial) {
    __shared__ __align__(16) ushort Asm[128 * 64];
    __shared__ __align__(16) ushort Bsm[128 * 64];

    int t = threadIdx.x;
    int lane = t & 63;
    int wid = t >> 6;
    int wm = wid >> 1, wn = wid & 1;
    int m0 = blockIdx.x * 128, n0 = blockIdx.y * 128;

    f32x4 acc[4][4] = {};

    for (int k0 = 0; k0 < CIN; k0 += 64) {
        #pragma unroll
        for (int i = 0; i < 4; ++i) {
            int idx = i * 256 + t;          // 0..1023
            int row = idx >> 3;
            int sl  = idx & 7;
            bf16x8 av = *reinterpret_cast<const bf16x8*>(A + (size_t)(m0 + row) * CIN + k0 + sl * 8);
            bf16x8 bv = *reinterpret_cast<const bf16x8*>(B + (size_t)(n0 + row) * CIN + k0 + sl * 8);
            int ws = (sl ^ (row & 7)) * 8;
            *reinterpret_cast<bf16x8*>(&Asm[row * 64 + ws]) = av;
            *reinterpret_cast<bf16x8*>(&Bsm[row * 64 + ws]) = bv;
        }
        __syncthreads();

        #pragma unroll
        for (int ks = 0; ks < 2; ++ks) {
            bf16x8 af[4], bfr[4];
            int slog = ks * 4 + (lane >> 4);
            #pragma unroll
            for (int mi = 0; mi < 4; ++mi) {
                int row = wm * 64 + mi * 16 + (lane & 15);
                af[mi] = *reinterpret_cast<const bf16x8*>(&Asm[row * 64 + (slog ^ (row & 7)) * 8]);
            }
            #pragma unroll
            for (int ni = 0; ni < 4; ++ni) {
                int col = wn * 64 + ni * 16 + (lane & 15);
                bfr[ni] = *reinterpret_cast<const bf16x8*>(&Bsm[col * 64 + (slog ^ (col & 7)) * 8]);
            }
            #pragma unroll
            for (int mi = 0; mi < 4; ++mi)
                #pragma unroll
                for (int ni = 0; ni < 4; ++ni)
                    acc[mi][ni] = __builtin_amdgcn_mfma_f32_16x16x32_bf16(af[mi], bfr[ni], acc[mi][ni], 0, 0, 0);
        }
        __syncthreads();
    }

    // fused column stats
    float s[4], q[4];
    #pragma unroll
    for (int ni = 0; ni < 4; ++ni) {
        s[ni] = 0.f; q[ni] = 0.f;
        #pragma unroll
        for (int mi = 0; mi < 4; ++mi)
            #pragma unroll
            for (int r = 0; r < 4; ++r) {
                float v = acc[mi][ni][r];
                s[ni] += v;
                q[ni] = fmaf(v, v, q[ni]);
            }
        s[ni] += __shfl_xor(s[ni], 16); s[ni] += __shfl_xor(s[ni], 32);
        q[ni] += __shfl_xor(q[ni], 16); q[ni] += __shfl_xor(q[ni], 32);
    }
    float* redS = (float*)Asm;
    float* redQ = redS + 256;
    if (lane < 16) {
        #pragma unroll
        for (int ni = 0; ni < 4; ++ni) {
            int c = wn * 64 + ni * 16 + lane;
            redS[wm * 128 + c] = s[ni];
            redQ[wm * 128 + c] = q[ni];
        }
    }
    __syncthreads();
    if (t < 128) {
        float S = redS[t] + redS[128 + t];
        float Q = redQ[t] + redQ[128 + t];
        partial[(size_t)blockIdx.x * 1024 + blockIdx.y * 128 + t]       = S;
        partial[(size_t)blockIdx.x * 1024 + 512 + blockIdx.y * 128 + t] = Q;
    }

    // H write (bf16)
    #pragma unroll
    for (int mi = 0; mi < 4; ++mi) {
        #pragma unroll
        for (int ni = 0; ni < 4; ++ni) {
            int col   = n0 + wn * 64 + ni * 16 + (lane & 15);
            int rbase = m0 + wm * 64 + mi * 16 + (lane >> 4) * 4;
            #pragma unroll
            for (int r = 0; r < 4; ++r)
                H[(size_t)(rbase + r) * COUT + col] = f2bf(acc[mi][ni][r]);
        }
    }
}

// ---------------------------------------------------------------------------
// Kernel C': parallel BN finalize — one block per column (champion).
// ---------------------------------------------------------------------------
__global__ __launch_bounds__(128) void bn_finalize_kernel(const float* __restrict__ partial,
                                                          const float* __restrict__ gamma,
                                                          const float* __restrict__ beta,
                                                          float* __restrict__ scale,
                                                          float* __restrict__ shift,
                                                          float invN) {
    __shared__ float sS[2], sQ[2];
    int c = blockIdx.x;                    // 0..511
    int p = threadIdx.x;                   // 0..127 (nparts == 128)
    float S = partial[(size_t)p * 1024 + c];
    float Q = partial[(size_t)p * 1024 + 512 + c];
    #pragma unroll
    for (int off = 1; off < 64; off <<= 1) {
        S += __shfl_xor(S, off);
        Q += __shfl_xor(Q, off);
    }
    int lane = p & 63, w = p >> 6;
    if (lane == 0) { sS[w] = S; sQ[w] = Q; }
    __syncthreads();
    if (p == 0) {
        float Sf = sS[0] + sS[1];
        float Qf = sQ[0] + sQ[1];
        float mean = Sf * invN;
        float var  = fmaf(Qf, invN, -mean * mean);
        float inv  = rsqrtf(var + 1e-5f);
        float sc   = gamma[c] * inv;
        scale[c] = sc;
        shift[c] = fmaf(-mean, sc, beta[c]);
    }
}

// ---------------------------------------------------------------------------
// Kernel D': normalize + relu + scatter (champion).
// ---------------------------------------------------------------------------
__global__ __launch_bounds__(256) void out_kernel(const ushort* __restrict__ H,
                                                  const int* __restrict__ inv4,
                                                  const float* __restrict__ scale,
                                                  const float* __restrict__ shift,
                                                  float* __restrict__ out, int rows) {
    __shared__ float scl[512], sht[512];
    int t = threadIdx.x;
    scl[t]       = scale[t];
    scl[t + 256] = scale[t + 256];
    sht[t]       = shift[t];
    sht[t + 256] = shift[t + 256];
    __syncthreads();

    int r = blockIdx.x * 32 + (t >> 3);    // this thread's row
    if (r >= rows) return;
    int c0 = (t & 7) * 8;                  // 8-col base; strides of 64 below
    int j = inv4[r];
    float* orow = out + (size_t)r * COUT;

    if (j >= 0) {
        const ushort* hrow = H + (size_t)j * COUT;
        #pragma unroll
        for (int i = 0; i < 8; ++i) {
            int c = c0 + i * 64;
            bf16x8 h = *reinterpret_cast<const bf16x8*>(hrow + c);
            float4 a, b;
            a.x = fmaxf(fmaf(bf2f((ushort)h[0]), scl[c + 0], sht[c + 0]), 0.f);
            a.y = fmaxf(fmaf(bf2f((ushort)h[1]), scl[c + 1], sht[c + 1]), 0.f);
            a.z = fmaxf(fmaf(bf2f((ushort)h[2]), scl[c + 2], sht[c + 2]), 0.f);
            a.w = fmaxf(fmaf(bf2f((ushort)h[3]), scl[c + 3], sht[c + 3]), 0.f);
            b.x = fmaxf(fmaf(bf2f((ushort)h[4]), scl[c + 4], sht[c + 4]), 0.f);
            b.y = fmaxf(fmaf(bf2f((ushort)h[5]), scl[c + 5], sht[c + 5]), 0.f);
            b.z = fmaxf(fmaf(bf2f((ushort)h[6]), scl[c + 6], sht[c + 6]), 0.f);
            b.w = fmaxf(fmaf(bf2f((ushort)h[7]), scl[c + 7], sht[c + 7]), 0.f);
            *reinterpret_cast<float4*>(orow + c)     = a;
            *reinterpret_cast<float4*>(orow + c + 4) = b;
        }
    } else {
        #pragma unroll
        for (int i = 0; i < 8; ++i) {
            int c = c0 + i * 64;
            float4 a, b;
            a.x = fmaxf(sht[c + 0], 0.f);
            a.y = fmaxf(sht[c + 1], 0.f);
            a.z = fmaxf(sht[c + 2], 0.f);
            a.w = fmaxf(sht[c + 3], 0.f);
            b.x = fmaxf(sht[c + 4], 0.f);
            b.y = fmaxf(sht[c + 5], 0.f);
            b.z = fmaxf(sht[c + 6], 0.f);
            b.w = fmaxf(sht[c + 7], 0.f);
            *reinterpret_cast<float4*>(orow + c)     = a;
            *reinterpret_cast<float4*>(orow + c + 4) = b;
        }
    }
}

// ---------------------------------------------------------------------------
extern "C" void kernel_launch(void* const* d_in, const int* in_sizes, int n_in,
                              void* d_out, int out_size, void* d_ws, size_t ws_size,
                              hipStream_t stream) {
    const float* data   = (const float*)d_in[0];
    const float* weight = (const float*)d_in[1];
    const float* gamma  = (const float*)d_in[2];
    const float* beta   = (const float*)d_in[3];
    const int*   idx5   = (const int*)d_in[4];
    const int*   idx4   = (const int*)d_in[5];

    const int n_i5 = in_sizes[4];        // 65536
    const int n_i4 = in_sizes[5];        // 16384
    const int G2   = n_i4;
    const int rows = out_size / COUT;    // 32768
    const int M    = G2;                 // 16384
    const int MB   = M / 128;            // 128 m-tiles

    // workspace layout
    char* w = (char*)d_ws;
    ushort* P      = (ushort*)w;                        w += (size_t)G2 * CIN * sizeof(ushort);    // 8 MiB
    ushort* H      = (ushort*)w;                        w += (size_t)G2 * COUT * sizeof(ushort);   // 16 MiB
    ushort* Wb     = (ushort*)w;                        w += (size_t)COUT * CIN * sizeof(ushort);  // 0.25 MiB
    float* partial = (float*)w;                         w += (size_t)MB * 1024 * sizeof(float);    // 512 KiB
    float* scale   = (float*)w;                         w += COUT * sizeof(float);
    float* shift   = (float*)w;                         w += COUT * sizeof(float);
    int*   inv4    = (int*)w;                           w += (size_t)rows * sizeof(int);           // 128 KiB

    // A: prep (96 blocks first) + pool (G2/8 blocks, 2 groups per wave)
    pool_prep_kernel<<<96 + G2 / 8, 256, 0, stream>>>(
        data, idx5, n_i5, idx4, n_i4, weight, Wb, P, G2, inv4, rows);

    // B: MFMA GEMM + fused stats (champion)
    {
        dim3 grid(MB, COUT / 128);
        mfma_gemm_kernel<<<grid, 256, 0, stream>>>(P, Wb, H, partial);
    }
    // C': parallel BN finalize (one block per column)
    bn_finalize_kernel<<<COUT, 128, 0, stream>>>(partial, gamma, beta, scale, shift,
                                                 1.0f / (float)rows);
    // D': normalize + relu + scatter (32 rows per block)
    out_kernel<<<(rows + 31) / 32, 256, 0, stream>>>(H, inv4, scale, shift,
                                                     (float*)d_out, rows);
}